// Round 1
// baseline (726.390 us; speedup 1.0000x reference)
//
#include <hip/hip_runtime.h>
#include <cstddef>
#include <cstdint>

// Problem constants (from reference): N=50000, F_IN=128, HID=64, HEADS=4, E=800000, NG=64
// Layer1: x[N,128] @ W1[128,256] -> h1[N,4,64]; GAT aggregate -> x2 = elu(agg + b1) [N,256]
// Layer2: x2 @ W2[256,64] -> h2[N,64]; GAT aggregate -> out2 = elu(agg + b2) [N,64]
// Pool: segment-mean by sorted batch -> [64,64]; fc -> [64]

__device__ __forceinline__ float lrelu02(float x) { return x >= 0.f ? x : 0.2f * x; }
__device__ __forceinline__ float elu1(float x)    { return x > 0.f ? x : expm1f(x); }

// ---------------- CSR build (by destination) ----------------
__global__ void k_hist(const int* __restrict__ dst, int* __restrict__ cnt, int e) {
    int i = blockIdx.x * 256 + threadIdx.x;
    if (i < e) atomicAdd(&cnt[dst[i]], 1);
}

__global__ __launch_bounds__(1024) void k_scan(const int* __restrict__ cnt,
                                               int* __restrict__ rowptr,
                                               int* __restrict__ fill, int n) {
    __shared__ int wsums[16];
    const int t = threadIdx.x, lane = t & 63, wv = t >> 6;
    int carry = 0;
    if (t == 0) rowptr[0] = 0;
    for (int base = 0; base < n; base += 1024) {
        int i = base + t;
        int v = (i < n) ? cnt[i] : 0;
        int s = v;
#pragma unroll
        for (int d = 1; d < 64; d <<= 1) { int o = __shfl_up(s, d); if (lane >= d) s += o; }
        if (lane == 63) wsums[wv] = s;
        __syncthreads();
        if (t < 16) {
            int xx = wsums[t];
#pragma unroll
            for (int d = 1; d < 16; d <<= 1) { int o = __shfl_up(xx, d); if (t >= d) xx += o; }
            wsums[t] = xx;
        }
        __syncthreads();
        int add = carry + (wv > 0 ? wsums[wv - 1] : 0);
        int incl = s + add;
        if (i < n) { rowptr[i + 1] = incl; fill[i] = incl - v; }
        carry += wsums[15];
        __syncthreads();
    }
}

__global__ void k_scatter(const int* __restrict__ src, const int* __restrict__ dstArr,
                          int* __restrict__ fill, int* __restrict__ csr, int e) {
    int i = blockIdx.x * 256 + threadIdx.x;
    if (i < e) {
        int d = dstArr[i];
        int p = atomicAdd(&fill[d], 1);
        csr[p] = src[i];
    }
}

// ---------------- fp32 tiled GEMM: C[M,NC] = A[M,K] @ B[K,NC] ----------------
template <int KC, int NC, int TY, int TX, int RT, int CT>
__global__ __launch_bounds__(TY * TX) void k_gemm(const float* __restrict__ A,
                                                  const float* __restrict__ B,
                                                  float* __restrict__ C, int M, int K) {
    constexpr int MT = TY * RT;
    __shared__ float As[MT][KC + 1];
    const int tid = threadIdx.x;
    const int tx = tid % TX, ty = tid / TX;
    const int row0 = blockIdx.x * MT;

    float acc[RT][CT];
#pragma unroll
    for (int j = 0; j < RT; ++j)
#pragma unroll
        for (int c = 0; c < CT; ++c) acc[j][c] = 0.f;

    for (int kc = 0; kc < K; kc += KC) {
        for (int f = tid; f < MT * (KC / 4); f += TY * TX) {
            int r = f / (KC / 4);
            int c4 = (f % (KC / 4)) * 4;
            float4 v = make_float4(0.f, 0.f, 0.f, 0.f);
            int gr = row0 + r;
            if (gr < M) v = *reinterpret_cast<const float4*>(A + (size_t)gr * K + kc + c4);
            As[r][c4 + 0] = v.x; As[r][c4 + 1] = v.y; As[r][c4 + 2] = v.z; As[r][c4 + 3] = v.w;
        }
        __syncthreads();
        const float* Bp = B + (size_t)kc * NC + tx * CT;
#pragma unroll 4
        for (int k = 0; k < KC; ++k) {
            float bv[CT];
#pragma unroll
            for (int q = 0; q < CT / 4; ++q) {
                float4 b4 = *reinterpret_cast<const float4*>(Bp + (size_t)k * NC + q * 4);
                bv[q * 4 + 0] = b4.x; bv[q * 4 + 1] = b4.y; bv[q * 4 + 2] = b4.z; bv[q * 4 + 3] = b4.w;
            }
#pragma unroll
            for (int j = 0; j < RT; ++j) {
                float a = As[ty * RT + j][k];
#pragma unroll
                for (int c = 0; c < CT; ++c) acc[j][c] = fmaf(a, bv[c], acc[j][c]);
            }
        }
        __syncthreads();
    }
#pragma unroll
    for (int j = 0; j < RT; ++j) {
        int gr = row0 + ty * RT + j;
        if (gr < M) {
#pragma unroll
            for (int q = 0; q < CT / 4; ++q) {
                float4 v = make_float4(acc[j][q * 4], acc[j][q * 4 + 1],
                                       acc[j][q * 4 + 2], acc[j][q * 4 + 3]);
                *reinterpret_cast<float4*>(C + (size_t)gr * NC + tx * CT + q * 4) = v;
            }
        }
    }
}

// ---------------- attention logits, layer 1: al[n,h] = sum_c h1[n,h,c]*a[h,c] ----------------
__global__ void k_al1(const float* __restrict__ h1, const float* __restrict__ a_src,
                      const float* __restrict__ a_dst, float* __restrict__ als,
                      float* __restrict__ ald, int n) {
    const int lane = threadIdx.x & 63;
    const int node = (blockIdx.x << 2) + (threadIdx.x >> 6);
    if (node >= n) return;
    const int head = lane >> 4;
    float4 hv = *reinterpret_cast<const float4*>(h1 + (size_t)node * 256 + lane * 4);
    float4 av = *reinterpret_cast<const float4*>(a_src + lane * 4);
    float4 dv = *reinterpret_cast<const float4*>(a_dst + lane * 4);
    float ps = hv.x * av.x + hv.y * av.y + hv.z * av.z + hv.w * av.w;
    float pd = hv.x * dv.x + hv.y * dv.y + hv.z * dv.z + hv.w * dv.w;
#pragma unroll
    for (int d = 1; d < 16; d <<= 1) { ps += __shfl_xor(ps, d); pd += __shfl_xor(pd, d); }
    if ((lane & 15) == 0) { als[node * 4 + head] = ps; ald[node * 4 + head] = pd; }
}

// ---------------- edge aggregation, layer 1 (wave per dst node) ----------------
__global__ void k_edge1(const float* __restrict__ h1, const float* __restrict__ als,
                        const float* __restrict__ ald, const int* __restrict__ rowptr,
                        const int* __restrict__ csr, const float* __restrict__ b1,
                        float* __restrict__ x2, int n) {
    const int lane = threadIdx.x & 63;
    const int node = (blockIdx.x << 2) + (threadIdx.x >> 6);
    if (node >= n) return;
    const int head = lane >> 4;
    const float adh = ald[node * 4 + head];
    float ax = 0.f, ay = 0.f, az = 0.f, aw = 0.f, wsum = 0.f;
    const int beg = rowptr[node], end = rowptr[node + 1];
    int i = beg;
    for (; i + 2 <= end; i += 2) {
        int s0 = csr[i], s1 = csr[i + 1];
        float a0 = als[s0 * 4 + head], a1 = als[s1 * 4 + head];
        float4 v0 = *reinterpret_cast<const float4*>(h1 + (size_t)s0 * 256 + lane * 4);
        float4 v1 = *reinterpret_cast<const float4*>(h1 + (size_t)s1 * 256 + lane * 4);
        float w0 = expf(lrelu02(a0 + adh));
        float w1 = expf(lrelu02(a1 + adh));
        ax += w0 * v0.x + w1 * v1.x;
        ay += w0 * v0.y + w1 * v1.y;
        az += w0 * v0.z + w1 * v1.z;
        aw += w0 * v0.w + w1 * v1.w;
        wsum += w0 + w1;
    }
    if (i < end) {
        int s0 = csr[i];
        float a0 = als[s0 * 4 + head];
        float4 v0 = *reinterpret_cast<const float4*>(h1 + (size_t)s0 * 256 + lane * 4);
        float w0 = expf(lrelu02(a0 + adh));
        ax += w0 * v0.x; ay += w0 * v0.y; az += w0 * v0.z; aw += w0 * v0.w;
        wsum += w0;
    }
    {   // self loop
        float a0 = als[node * 4 + head];
        float4 v0 = *reinterpret_cast<const float4*>(h1 + (size_t)node * 256 + lane * 4);
        float w0 = expf(lrelu02(a0 + adh));
        ax += w0 * v0.x; ay += w0 * v0.y; az += w0 * v0.z; aw += w0 * v0.w;
        wsum += w0;
    }
    const float inv = 1.f / (wsum + 1e-16f);
    float4 bv = *reinterpret_cast<const float4*>(b1 + lane * 4);
    float4 r;
    r.x = elu1(ax * inv + bv.x);
    r.y = elu1(ay * inv + bv.y);
    r.z = elu1(az * inv + bv.z);
    r.w = elu1(aw * inv + bv.w);
    *reinterpret_cast<float4*>(x2 + (size_t)node * 256 + lane * 4) = r;
}

// ---------------- attention logits, layer 2 (single head over 64 ch) ----------------
__global__ void k_al2(const float* __restrict__ h2, const float* __restrict__ a_src,
                      const float* __restrict__ a_dst, float* __restrict__ als,
                      float* __restrict__ ald, int n) {
    const int lane = threadIdx.x & 63;
    const int node = (blockIdx.x << 2) + (threadIdx.x >> 6);
    if (node >= n) return;
    float hv = h2[(size_t)node * 64 + lane];
    float ps = hv * a_src[lane];
    float pd = hv * a_dst[lane];
#pragma unroll
    for (int d = 1; d < 64; d <<= 1) { ps += __shfl_xor(ps, d); pd += __shfl_xor(pd, d); }
    if (lane == 0) { als[node] = ps; ald[node] = pd; }
}

// ---------------- edge aggregation, layer 2 ----------------
__global__ void k_edge2(const float* __restrict__ h2, const float* __restrict__ als,
                        const float* __restrict__ ald, const int* __restrict__ rowptr,
                        const int* __restrict__ csr, const float* __restrict__ b2,
                        float* __restrict__ out2, int n) {
    const int lane = threadIdx.x & 63;
    const int node = (blockIdx.x << 2) + (threadIdx.x >> 6);
    if (node >= n) return;
    const float adh = ald[node];
    float acc = 0.f, wsum = 0.f;
    const int beg = rowptr[node], end = rowptr[node + 1];
    int i = beg;
    for (; i + 2 <= end; i += 2) {
        int s0 = csr[i], s1 = csr[i + 1];
        float a0 = als[s0], a1 = als[s1];
        float v0 = h2[(size_t)s0 * 64 + lane];
        float v1 = h2[(size_t)s1 * 64 + lane];
        float w0 = expf(lrelu02(a0 + adh));
        float w1 = expf(lrelu02(a1 + adh));
        acc += w0 * v0 + w1 * v1;
        wsum += w0 + w1;
    }
    if (i < end) {
        int s0 = csr[i];
        float w0 = expf(lrelu02(als[s0] + adh));
        acc += w0 * h2[(size_t)s0 * 64 + lane];
        wsum += w0;
    }
    {   // self loop
        float w0 = expf(lrelu02(als[node] + adh));
        acc += w0 * h2[(size_t)node * 64 + lane];
        wsum += w0;
    }
    float o = acc / (wsum + 1e-16f) + b2[lane];
    out2[(size_t)node * 64 + lane] = elu1(o);
}

// ---------------- pool (mean by sorted batch) + fc ----------------
__global__ void k_pool(const float* __restrict__ out2, const int* __restrict__ batch,
                       const float* __restrict__ fcW, const float* __restrict__ fcb,
                       float* __restrict__ out, int n) {
    const int g = blockIdx.x, lane = threadIdx.x;  // blockDim = 64
    // lower_bound(batch, g) and lower_bound(batch, g+1) — batch is sorted
    int lo0 = 0, hi0 = n;
    while (lo0 < hi0) { int mid = (lo0 + hi0) >> 1; if (batch[mid] < g) lo0 = mid + 1; else hi0 = mid; }
    int lo1 = lo0, hi1 = n;
    while (lo1 < hi1) { int mid = (lo1 + hi1) >> 1; if (batch[mid] < g + 1) lo1 = mid + 1; else hi1 = mid; }
    float sum = 0.f;
    for (int r = lo0; r < lo1; ++r) sum += out2[(size_t)r * 64 + lane];
    float cntf = (float)(lo1 - lo0);
    float pooled = sum / fmaxf(cntf, 1.f);
    float v = pooled * fcW[lane];
#pragma unroll
    for (int d = 32; d; d >>= 1) v += __shfl_xor(v, d);
    if (lane == 0) out[g] = v + fcb[0];
}

// ---------------- host launcher ----------------
extern "C" void kernel_launch(void* const* d_in, const int* in_sizes, int n_in,
                              void* d_out, int out_size, void* d_ws, size_t ws_size,
                              hipStream_t stream) {
    const float* x      = (const float*)d_in[0];
    const int*   ei     = (const int*)  d_in[1];
    const int*   batch  = (const int*)  d_in[2];
    const float* W1     = (const float*)d_in[3];
    const float* a_src1 = (const float*)d_in[4];
    const float* a_dst1 = (const float*)d_in[5];
    const float* b1     = (const float*)d_in[6];
    const float* W2     = (const float*)d_in[7];
    const float* a_src2 = (const float*)d_in[8];
    const float* a_dst2 = (const float*)d_in[9];
    const float* b2     = (const float*)d_in[10];
    const float* fcW    = (const float*)d_in[11];
    const float* fcb    = (const float*)d_in[12];
    float* out = (float*)d_out;

    const int N = in_sizes[2];
    const int E = in_sizes[1] / 2;
    (void)n_in; (void)ws_size;

    char* ws = (char*)d_ws;
    size_t off = 0;
    auto alloc = [&](size_t bytes) -> char* {
        char* p = ws + off;
        off += (bytes + 255) & ~(size_t)255;
        return p;
    };
    int*   cnt    = (int*)  alloc((size_t)N * 4);
    int*   fill   = (int*)  alloc((size_t)N * 4);
    int*   rowptr = (int*)  alloc((size_t)(N + 1) * 4);
    int*   csr    = (int*)  alloc((size_t)E * 4);
    float* h1     = (float*)alloc((size_t)N * 256 * 4);
    float* x2     = (float*)alloc((size_t)N * 256 * 4);
    float* h2     = (float*)alloc((size_t)N * 64 * 4);
    float* out2   = (float*)alloc((size_t)N * 64 * 4);
    float* als1   = (float*)alloc((size_t)N * 4 * 4);
    float* ald1   = (float*)alloc((size_t)N * 4 * 4);
    float* als2   = (float*)alloc((size_t)N * 4);
    float* ald2   = (float*)alloc((size_t)N * 4);

    hipMemsetAsync(cnt, 0, (size_t)N * 4, stream);
    const int ge = (E + 255) / 256;
    k_hist<<<ge, 256, 0, stream>>>(ei + E, cnt, E);
    k_scan<<<1, 1024, 0, stream>>>(cnt, rowptr, fill, N);
    k_scatter<<<ge, 256, 0, stream>>>(ei, ei + E, fill, csr, E);

    // Layer 1
    k_gemm<128, 256, 16, 16, 4, 16><<<(N + 63) / 64, 256, 0, stream>>>(x, W1, h1, N, 128);
    const int gn4 = (N + 3) / 4;
    k_al1<<<gn4, 256, 0, stream>>>(h1, a_src1, a_dst1, als1, ald1, N);
    k_edge1<<<gn4, 256, 0, stream>>>(h1, als1, ald1, rowptr, csr, b1, x2, N);

    // Layer 2
    k_gemm<64, 64, 32, 8, 4, 8><<<(N + 127) / 128, 256, 0, stream>>>(x2, W2, h2, N, 256);
    k_al2<<<gn4, 256, 0, stream>>>(h2, a_src2, a_dst2, als2, ald2, N);
    k_edge2<<<gn4, 256, 0, stream>>>(h2, als2, ald2, rowptr, csr, b2, out2, N);

    // Pool + FC
    k_pool<<<out_size, 64, 0, stream>>>(out2, batch, fcW, fcb, out, N);
}

// Round 2
// 531.865 us; speedup vs baseline: 1.3657x; 1.3657x over previous
//
#include <hip/hip_runtime.h>
#include <cstddef>
#include <cstdint>

// Problem constants (from reference): N=50000, F_IN=128, HID=64, HEADS=4, E=800000, NG=64
// Layer1: x[N,128] @ W1[128,256] -> h1[N,4,64]; GAT aggregate -> x2 = elu(agg + b1) [N,256]
// Layer2: x2 @ W2[256,64] -> h2[N,64]; GAT aggregate -> out2 = elu(agg + b2) [N,64]
// Pool: segment-mean by sorted batch -> [64,64]; fc -> [64]

__device__ __forceinline__ float lrelu02(float x) { return x >= 0.f ? x : 0.2f * x; }
__device__ __forceinline__ float elu1(float x)    { return x > 0.f ? x : expm1f(x); }

// ---------------- CSR build (by destination) ----------------
__global__ void k_hist(const int* __restrict__ dst, int* __restrict__ cnt, int e) {
    int i = blockIdx.x * 256 + threadIdx.x;
    if (i < e) atomicAdd(&cnt[dst[i]], 1);
}

__global__ __launch_bounds__(1024) void k_scan(const int* __restrict__ cnt,
                                               int* __restrict__ rowptr,
                                               int* __restrict__ fill, int n) {
    __shared__ int wsums[16];
    const int t = threadIdx.x, lane = t & 63, wv = t >> 6;
    int carry = 0;
    if (t == 0) rowptr[0] = 0;
    for (int base = 0; base < n; base += 1024) {
        int i = base + t;
        int v = (i < n) ? cnt[i] : 0;
        int s = v;
#pragma unroll
        for (int d = 1; d < 64; d <<= 1) { int o = __shfl_up(s, d); if (lane >= d) s += o; }
        if (lane == 63) wsums[wv] = s;
        __syncthreads();
        if (t < 16) {
            int xx = wsums[t];
#pragma unroll
            for (int d = 1; d < 16; d <<= 1) { int o = __shfl_up(xx, d); if (t >= d) xx += o; }
            wsums[t] = xx;
        }
        __syncthreads();
        int add = carry + (wv > 0 ? wsums[wv - 1] : 0);
        int incl = s + add;
        if (i < n) { rowptr[i + 1] = incl; fill[i] = incl - v; }
        carry += wsums[15];
        __syncthreads();
    }
}

__global__ void k_scatter(const int* __restrict__ src, const int* __restrict__ dstArr,
                          int* __restrict__ fill, int* __restrict__ csr, int e) {
    int i = blockIdx.x * 256 + threadIdx.x;
    if (i < e) {
        int d = dstArr[i];
        int p = atomicAdd(&fill[d], 1);
        csr[p] = src[i];
    }
}

// ---------------- fp32 tiled GEMM: C[M,NC] = A[M,K] @ B[K,NC] ----------------
template <int KC, int NC, int TY, int TX, int RT, int CT>
__global__ __launch_bounds__(TY * TX) void k_gemm(const float* __restrict__ A,
                                                  const float* __restrict__ B,
                                                  float* __restrict__ C, int M, int K) {
    constexpr int MT = TY * RT;
    __shared__ float As[MT][KC + 1];
    const int tid = threadIdx.x;
    const int tx = tid % TX, ty = tid / TX;
    const int row0 = blockIdx.x * MT;

    float acc[RT][CT];
#pragma unroll
    for (int j = 0; j < RT; ++j)
#pragma unroll
        for (int c = 0; c < CT; ++c) acc[j][c] = 0.f;

    for (int kc = 0; kc < K; kc += KC) {
        for (int f = tid; f < MT * (KC / 4); f += TY * TX) {
            int r = f / (KC / 4);
            int c4 = (f % (KC / 4)) * 4;
            float4 v = make_float4(0.f, 0.f, 0.f, 0.f);
            int gr = row0 + r;
            if (gr < M) v = *reinterpret_cast<const float4*>(A + (size_t)gr * K + kc + c4);
            As[r][c4 + 0] = v.x; As[r][c4 + 1] = v.y; As[r][c4 + 2] = v.z; As[r][c4 + 3] = v.w;
        }
        __syncthreads();
        const float* Bp = B + (size_t)kc * NC + tx * CT;
#pragma unroll 4
        for (int k = 0; k < KC; ++k) {
            float bv[CT];
#pragma unroll
            for (int q = 0; q < CT / 4; ++q) {
                float4 b4 = *reinterpret_cast<const float4*>(Bp + (size_t)k * NC + q * 4);
                bv[q * 4 + 0] = b4.x; bv[q * 4 + 1] = b4.y; bv[q * 4 + 2] = b4.z; bv[q * 4 + 3] = b4.w;
            }
#pragma unroll
            for (int j = 0; j < RT; ++j) {
                float a = As[ty * RT + j][k];
#pragma unroll
                for (int c = 0; c < CT; ++c) acc[j][c] = fmaf(a, bv[c], acc[j][c]);
            }
        }
        __syncthreads();
    }
#pragma unroll
    for (int j = 0; j < RT; ++j) {
        int gr = row0 + ty * RT + j;
        if (gr < M) {
#pragma unroll
            for (int q = 0; q < CT / 4; ++q) {
                float4 v = make_float4(acc[j][q * 4], acc[j][q * 4 + 1],
                                       acc[j][q * 4 + 2], acc[j][q * 4 + 3]);
                *reinterpret_cast<float4*>(C + (size_t)gr * NC + tx * CT + q * 4) = v;
            }
        }
    }
}

// ---------------- attention logits, layer 1: al[n,h] = sum_c h1[n,h,c]*a[h,c] ----------------
__global__ void k_al1(const float* __restrict__ h1, const float* __restrict__ a_src,
                      const float* __restrict__ a_dst, float* __restrict__ als,
                      float* __restrict__ ald, int n) {
    const int lane = threadIdx.x & 63;
    const int node = (blockIdx.x << 2) + (threadIdx.x >> 6);
    if (node >= n) return;
    const int head = lane >> 4;
    float4 hv = *reinterpret_cast<const float4*>(h1 + (size_t)node * 256 + lane * 4);
    float4 av = *reinterpret_cast<const float4*>(a_src + lane * 4);
    float4 dv = *reinterpret_cast<const float4*>(a_dst + lane * 4);
    float ps = hv.x * av.x + hv.y * av.y + hv.z * av.z + hv.w * av.w;
    float pd = hv.x * dv.x + hv.y * dv.y + hv.z * dv.z + hv.w * dv.w;
#pragma unroll
    for (int d = 1; d < 16; d <<= 1) { ps += __shfl_xor(ps, d); pd += __shfl_xor(pd, d); }
    if ((lane & 15) == 0) { als[node * 4 + head] = ps; ald[node * 4 + head] = pd; }
}

// ---------------- edge aggregation, layer 1 (wave per dst node) ----------------
__global__ void k_edge1(const float* __restrict__ h1, const float* __restrict__ als,
                        const float* __restrict__ ald, const int* __restrict__ rowptr,
                        const int* __restrict__ csr, const float* __restrict__ b1,
                        float* __restrict__ x2, int n) {
    const int lane = threadIdx.x & 63;
    const int node = (blockIdx.x << 2) + (threadIdx.x >> 6);
    if (node >= n) return;
    const int head = lane >> 4;
    const float adh = ald[node * 4 + head];
    float ax = 0.f, ay = 0.f, az = 0.f, aw = 0.f, wsum = 0.f;
    const int beg = rowptr[node], end = rowptr[node + 1];
    int i = beg;
    for (; i + 2 <= end; i += 2) {
        int s0 = csr[i], s1 = csr[i + 1];
        float a0 = als[s0 * 4 + head], a1 = als[s1 * 4 + head];
        float4 v0 = *reinterpret_cast<const float4*>(h1 + (size_t)s0 * 256 + lane * 4);
        float4 v1 = *reinterpret_cast<const float4*>(h1 + (size_t)s1 * 256 + lane * 4);
        float w0 = expf(lrelu02(a0 + adh));
        float w1 = expf(lrelu02(a1 + adh));
        ax += w0 * v0.x + w1 * v1.x;
        ay += w0 * v0.y + w1 * v1.y;
        az += w0 * v0.z + w1 * v1.z;
        aw += w0 * v0.w + w1 * v1.w;
        wsum += w0 + w1;
    }
    if (i < end) {
        int s0 = csr[i];
        float a0 = als[s0 * 4 + head];
        float4 v0 = *reinterpret_cast<const float4*>(h1 + (size_t)s0 * 256 + lane * 4);
        float w0 = expf(lrelu02(a0 + adh));
        ax += w0 * v0.x; ay += w0 * v0.y; az += w0 * v0.z; aw += w0 * v0.w;
        wsum += w0;
    }
    {   // self loop
        float a0 = als[node * 4 + head];
        float4 v0 = *reinterpret_cast<const float4*>(h1 + (size_t)node * 256 + lane * 4);
        float w0 = expf(lrelu02(a0 + adh));
        ax += w0 * v0.x; ay += w0 * v0.y; az += w0 * v0.z; aw += w0 * v0.w;
        wsum += w0;
    }
    const float inv = 1.f / (wsum + 1e-16f);
    float4 bv = *reinterpret_cast<const float4*>(b1 + lane * 4);
    float4 r;
    r.x = elu1(ax * inv + bv.x);
    r.y = elu1(ay * inv + bv.y);
    r.z = elu1(az * inv + bv.z);
    r.w = elu1(aw * inv + bv.w);
    *reinterpret_cast<float4*>(x2 + (size_t)node * 256 + lane * 4) = r;
}

// ---------------- attention logits, layer 2 (single head over 64 ch) ----------------
__global__ void k_al2(const float* __restrict__ h2, const float* __restrict__ a_src,
                      const float* __restrict__ a_dst, float* __restrict__ als,
                      float* __restrict__ ald, int n) {
    const int lane = threadIdx.x & 63;
    const int node = (blockIdx.x << 2) + (threadIdx.x >> 6);
    if (node >= n) return;
    float hv = h2[(size_t)node * 64 + lane];
    float ps = hv * a_src[lane];
    float pd = hv * a_dst[lane];
#pragma unroll
    for (int d = 1; d < 64; d <<= 1) { ps += __shfl_xor(ps, d); pd += __shfl_xor(pd, d); }
    if (lane == 0) { als[node] = ps; ald[node] = pd; }
}

// ---------------- edge aggregation, layer 2 ----------------
__global__ void k_edge2(const float* __restrict__ h2, const float* __restrict__ als,
                        const float* __restrict__ ald, const int* __restrict__ rowptr,
                        const int* __restrict__ csr, const float* __restrict__ b2,
                        float* __restrict__ out2, int n) {
    const int lane = threadIdx.x & 63;
    const int node = (blockIdx.x << 2) + (threadIdx.x >> 6);
    if (node >= n) return;
    const float adh = ald[node];
    float acc = 0.f, wsum = 0.f;
    const int beg = rowptr[node], end = rowptr[node + 1];
    int i = beg;
    for (; i + 2 <= end; i += 2) {
        int s0 = csr[i], s1 = csr[i + 1];
        float a0 = als[s0], a1 = als[s1];
        float v0 = h2[(size_t)s0 * 64 + lane];
        float v1 = h2[(size_t)s1 * 64 + lane];
        float w0 = expf(lrelu02(a0 + adh));
        float w1 = expf(lrelu02(a1 + adh));
        acc += w0 * v0 + w1 * v1;
        wsum += w0 + w1;
    }
    if (i < end) {
        int s0 = csr[i];
        float w0 = expf(lrelu02(als[s0] + adh));
        acc += w0 * h2[(size_t)s0 * 64 + lane];
        wsum += w0;
    }
    {   // self loop
        float w0 = expf(lrelu02(als[node] + adh));
        acc += w0 * h2[(size_t)node * 64 + lane];
        wsum += w0;
    }
    float o = acc / (wsum + 1e-16f) + b2[lane];
    out2[(size_t)node * 64 + lane] = elu1(o);
}

// ---------------- pool (mean by sorted batch) + fc ----------------
// One 1024-thread block per graph: 16 waves stride the graph's node range
// (lane = channel; each row = one coalesced 256B wave read), LDS-reduce the
// 16 wave partials, wave 0 applies mean + fc. Deterministic (no float atomics).
__global__ __launch_bounds__(1024) void k_pool(const float* __restrict__ out2,
                                               const int* __restrict__ batch,
                                               const float* __restrict__ fcW,
                                               const float* __restrict__ fcb,
                                               float* __restrict__ out, int n) {
    __shared__ float sbuf[16][64];
    const int g = blockIdx.x;
    const int lane = threadIdx.x & 63, wv = threadIdx.x >> 6;
    // segment bounds via binary search (batch sorted); uniform across block
    int lo0 = 0, hi0 = n;
    while (lo0 < hi0) { int mid = (lo0 + hi0) >> 1; if (batch[mid] < g) lo0 = mid + 1; else hi0 = mid; }
    int lo1 = lo0, hi1 = n;
    while (lo1 < hi1) { int mid = (lo1 + hi1) >> 1; if (batch[mid] < g + 1) lo1 = mid + 1; else hi1 = mid; }
    // two independent accumulators (stride 32 rows) for memory-level parallelism
    float s0 = 0.f, s1 = 0.f;
    int r = lo0 + wv;
    for (; r + 16 < lo1; r += 32) {
        s0 += out2[(size_t)r * 64 + lane];
        s1 += out2[(size_t)(r + 16) * 64 + lane];
    }
    if (r < lo1) s0 += out2[(size_t)r * 64 + lane];
    sbuf[wv][lane] = s0 + s1;
    __syncthreads();
    if (wv == 0) {
        float s = 0.f;
#pragma unroll
        for (int k = 0; k < 16; ++k) s += sbuf[k][lane];
        float cntf = (float)(lo1 - lo0);
        float pooled = s / fmaxf(cntf, 1.f);
        float v = pooled * fcW[lane];
#pragma unroll
        for (int d = 32; d; d >>= 1) v += __shfl_xor(v, d);
        if (lane == 0) out[g] = v + fcb[0];
    }
}

// ---------------- host launcher ----------------
extern "C" void kernel_launch(void* const* d_in, const int* in_sizes, int n_in,
                              void* d_out, int out_size, void* d_ws, size_t ws_size,
                              hipStream_t stream) {
    const float* x      = (const float*)d_in[0];
    const int*   ei     = (const int*)  d_in[1];
    const int*   batch  = (const int*)  d_in[2];
    const float* W1     = (const float*)d_in[3];
    const float* a_src1 = (const float*)d_in[4];
    const float* a_dst1 = (const float*)d_in[5];
    const float* b1     = (const float*)d_in[6];
    const float* W2     = (const float*)d_in[7];
    const float* a_src2 = (const float*)d_in[8];
    const float* a_dst2 = (const float*)d_in[9];
    const float* b2     = (const float*)d_in[10];
    const float* fcW    = (const float*)d_in[11];
    const float* fcb    = (const float*)d_in[12];
    float* out = (float*)d_out;

    const int N = in_sizes[2];
    const int E = in_sizes[1] / 2;
    (void)n_in; (void)ws_size;

    char* ws = (char*)d_ws;
    size_t off = 0;
    auto alloc = [&](size_t bytes) -> char* {
        char* p = ws + off;
        off += (bytes + 255) & ~(size_t)255;
        return p;
    };
    int*   cnt    = (int*)  alloc((size_t)N * 4);
    int*   fill   = (int*)  alloc((size_t)N * 4);
    int*   rowptr = (int*)  alloc((size_t)(N + 1) * 4);
    int*   csr    = (int*)  alloc((size_t)E * 4);
    float* h1     = (float*)alloc((size_t)N * 256 * 4);
    float* x2     = (float*)alloc((size_t)N * 256 * 4);
    float* h2     = (float*)alloc((size_t)N * 64 * 4);
    float* out2   = (float*)alloc((size_t)N * 64 * 4);
    float* als1   = (float*)alloc((size_t)N * 4 * 4);
    float* ald1   = (float*)alloc((size_t)N * 4 * 4);
    float* als2   = (float*)alloc((size_t)N * 4);
    float* ald2   = (float*)alloc((size_t)N * 4);

    hipMemsetAsync(cnt, 0, (size_t)N * 4, stream);
    const int ge = (E + 255) / 256;
    k_hist<<<ge, 256, 0, stream>>>(ei + E, cnt, E);
    k_scan<<<1, 1024, 0, stream>>>(cnt, rowptr, fill, N);
    k_scatter<<<ge, 256, 0, stream>>>(ei, ei + E, fill, csr, E);

    // Layer 1
    k_gemm<128, 256, 16, 16, 4, 16><<<(N + 63) / 64, 256, 0, stream>>>(x, W1, h1, N, 128);
    const int gn4 = (N + 3) / 4;
    k_al1<<<gn4, 256, 0, stream>>>(h1, a_src1, a_dst1, als1, ald1, N);
    k_edge1<<<gn4, 256, 0, stream>>>(h1, als1, ald1, rowptr, csr, b1, x2, N);

    // Layer 2
    k_gemm<64, 64, 32, 8, 4, 8><<<(N + 127) / 128, 256, 0, stream>>>(x2, W2, h2, N, 256);
    k_al2<<<gn4, 256, 0, stream>>>(h2, a_src2, a_dst2, als2, ald2, N);
    k_edge2<<<gn4, 256, 0, stream>>>(h2, als2, ald2, rowptr, csr, b2, out2, N);

    // Pool + FC
    k_pool<<<out_size, 1024, 0, stream>>>(out2, batch, fcW, fcb, out, N);
}

// Round 3
// 507.135 us; speedup vs baseline: 1.4323x; 1.0488x over previous
//
#include <hip/hip_runtime.h>
#include <cstddef>
#include <cstdint>

// Problem constants (from reference): N=50000, F_IN=128, HID=64, HEADS=4, E=800000, NG=64
// Layer1: x[N,128] @ W1[128,256] -> h1[N,4,64]; GAT aggregate -> x2 = elu(agg + b1) [N,256]
// Layer2: x2 @ W2[256,64] -> h2[N,64]; GAT aggregate -> out2 = elu(agg + b2) [N,64]
// Pool: segment-mean by sorted batch -> [64,64]; fc -> [64]

__device__ __forceinline__ float lrelu02(float x) { return x >= 0.f ? x : 0.2f * x; }
__device__ __forceinline__ float elu1(float x)    { return x > 0.f ? x : expm1f(x); }

// ---------------- CSR build (by destination) ----------------
__global__ void k_hist(const int* __restrict__ dst, int* __restrict__ cnt, int e) {
    int i = blockIdx.x * 256 + threadIdx.x;
    if (i < e) atomicAdd(&cnt[dst[i]], 1);
}

__global__ __launch_bounds__(1024) void k_scan(const int* __restrict__ cnt,
                                               int* __restrict__ rowptr,
                                               int* __restrict__ fill, int n) {
    __shared__ int wsums[16];
    const int t = threadIdx.x, lane = t & 63, wv = t >> 6;
    int carry = 0;
    if (t == 0) rowptr[0] = 0;
    for (int base = 0; base < n; base += 1024) {
        int i = base + t;
        int v = (i < n) ? cnt[i] : 0;
        int s = v;
#pragma unroll
        for (int d = 1; d < 64; d <<= 1) { int o = __shfl_up(s, d); if (lane >= d) s += o; }
        if (lane == 63) wsums[wv] = s;
        __syncthreads();
        if (t < 16) {
            int xx = wsums[t];
#pragma unroll
            for (int d = 1; d < 16; d <<= 1) { int o = __shfl_up(xx, d); if (t >= d) xx += o; }
            wsums[t] = xx;
        }
        __syncthreads();
        int add = carry + (wv > 0 ? wsums[wv - 1] : 0);
        int incl = s + add;
        if (i < n) { rowptr[i + 1] = incl; fill[i] = incl - v; }
        carry += wsums[15];
        __syncthreads();
    }
}

__global__ void k_scatter(const int* __restrict__ src, const int* __restrict__ dstArr,
                          int* __restrict__ fill, int* __restrict__ csr, int e) {
    int i = blockIdx.x * 256 + threadIdx.x;
    if (i < e) {
        int d = dstArr[i];
        int p = atomicAdd(&fill[d], 1);
        csr[p] = src[i];
    }
}

// ---------------- fp32 register-blocked GEMM: C[M,NC] = A[M,K] @ B[K,NC] ----------------
// A and B tiles staged in LDS (A stored k-major), 8x8 accumulator per thread,
// register prefetch of next tile's global loads over current tile's FMAs.
// Requires: K % BK == 0, NC % BN == 0, BM == 8*TY, BN == 8*TX.
template <int BM, int BN, int BK, int TX, int TY>
__global__ __launch_bounds__(TX * TY) void k_gemm_t(const float* __restrict__ A,
                                                    const float* __restrict__ B,
                                                    float* __restrict__ C,
                                                    int M, int K, int NC) {
    constexpr int NT = TX * TY;
    constexpr int LA = (BM * BK) / (4 * NT);   // float4 A-loads per thread
    constexpr int LB = (BK * BN) / (4 * NT);   // float4 B-loads per thread
    __shared__ float As[BK][BM + 4];           // k-major; +4 keeps 16B align, 2-way banks
    __shared__ float Bs[BK][BN + 4];

    const int tid = threadIdx.x;
    const int tx = tid % TX, ty = tid / TX;
    const int nbn = NC / BN;
    const int bx = blockIdx.x / nbn;           // consecutive blocks share A panel (L2 reuse)
    const int by = blockIdx.x % nbn;
    const int row0 = bx * BM, col0 = by * BN;

    float4 pa[LA], pb[LB];
    auto loadA = [&](int kc) {
#pragma unroll
        for (int i = 0; i < LA; ++i) {
            int g = tid + i * NT;
            int m = g / (BK / 4), kq = (g % (BK / 4)) * 4;
            int gr = row0 + m;
            pa[i] = (gr < M) ? *reinterpret_cast<const float4*>(A + (size_t)gr * K + kc + kq)
                             : make_float4(0.f, 0.f, 0.f, 0.f);
        }
    };
    auto loadB = [&](int kc) {
#pragma unroll
        for (int i = 0; i < LB; ++i) {
            int g = tid + i * NT;
            int k = g / (BN / 4), n4 = (g % (BN / 4)) * 4;
            pb[i] = *reinterpret_cast<const float4*>(B + (size_t)(kc + k) * NC + col0 + n4);
        }
    };
    auto storeLDS = [&]() {
#pragma unroll
        for (int i = 0; i < LA; ++i) {
            int g = tid + i * NT;
            int m = g / (BK / 4), kq = (g % (BK / 4)) * 4;
            As[kq + 0][m] = pa[i].x; As[kq + 1][m] = pa[i].y;
            As[kq + 2][m] = pa[i].z; As[kq + 3][m] = pa[i].w;
        }
#pragma unroll
        for (int i = 0; i < LB; ++i) {
            int g = tid + i * NT;
            int k = g / (BN / 4), n4 = (g % (BN / 4)) * 4;
            *reinterpret_cast<float4*>(&Bs[k][n4]) = pb[i];
        }
    };

    float acc[8][8];
#pragma unroll
    for (int i = 0; i < 8; ++i)
#pragma unroll
        for (int j = 0; j < 8; ++j) acc[i][j] = 0.f;

    loadA(0); loadB(0);
    storeLDS();
    __syncthreads();
    const int TI = K / BK;
    for (int t = 0; t < TI; ++t) {
        if (t + 1 < TI) { loadA((t + 1) * BK); loadB((t + 1) * BK); }
#pragma unroll
        for (int k = 0; k < BK; ++k) {
            float4 a0 = *reinterpret_cast<const float4*>(&As[k][ty * 8]);
            float4 a1 = *reinterpret_cast<const float4*>(&As[k][ty * 8 + 4]);
            float4 b0 = *reinterpret_cast<const float4*>(&Bs[k][tx * 8]);
            float4 b1 = *reinterpret_cast<const float4*>(&Bs[k][tx * 8 + 4]);
            float av[8] = {a0.x, a0.y, a0.z, a0.w, a1.x, a1.y, a1.z, a1.w};
            float bv[8] = {b0.x, b0.y, b0.z, b0.w, b1.x, b1.y, b1.z, b1.w};
#pragma unroll
            for (int i = 0; i < 8; ++i)
#pragma unroll
                for (int j = 0; j < 8; ++j) acc[i][j] = fmaf(av[i], bv[j], acc[i][j]);
        }
        if (t + 1 < TI) {
            __syncthreads();
            storeLDS();
            __syncthreads();
        }
    }
#pragma unroll
    for (int i = 0; i < 8; ++i) {
        int gr = row0 + ty * 8 + i;
        if (gr < M) {
            *reinterpret_cast<float4*>(C + (size_t)gr * NC + col0 + tx * 8) =
                make_float4(acc[i][0], acc[i][1], acc[i][2], acc[i][3]);
            *reinterpret_cast<float4*>(C + (size_t)gr * NC + col0 + tx * 8 + 4) =
                make_float4(acc[i][4], acc[i][5], acc[i][6], acc[i][7]);
        }
    }
}

// ---------------- attention logits, layer 1: al[n,h] = sum_c h1[n,h,c]*a[h,c] ----------------
__global__ void k_al1(const float* __restrict__ h1, const float* __restrict__ a_src,
                      const float* __restrict__ a_dst, float* __restrict__ als,
                      float* __restrict__ ald, int n) {
    const int lane = threadIdx.x & 63;
    const int node = (blockIdx.x << 2) + (threadIdx.x >> 6);
    if (node >= n) return;
    const int head = lane >> 4;
    float4 hv = *reinterpret_cast<const float4*>(h1 + (size_t)node * 256 + lane * 4);
    float4 av = *reinterpret_cast<const float4*>(a_src + lane * 4);
    float4 dv = *reinterpret_cast<const float4*>(a_dst + lane * 4);
    float ps = hv.x * av.x + hv.y * av.y + hv.z * av.z + hv.w * av.w;
    float pd = hv.x * dv.x + hv.y * dv.y + hv.z * dv.z + hv.w * dv.w;
#pragma unroll
    for (int d = 1; d < 16; d <<= 1) { ps += __shfl_xor(ps, d); pd += __shfl_xor(pd, d); }
    if ((lane & 15) == 0) { als[node * 4 + head] = ps; ald[node * 4 + head] = pd; }
}

// ---------------- edge aggregation, layer 1 (wave per dst node) ----------------
__global__ void k_edge1(const float* __restrict__ h1, const float* __restrict__ als,
                        const float* __restrict__ ald, const int* __restrict__ rowptr,
                        const int* __restrict__ csr, const float* __restrict__ b1,
                        float* __restrict__ x2, int n) {
    const int lane = threadIdx.x & 63;
    const int node = (blockIdx.x << 2) + (threadIdx.x >> 6);
    if (node >= n) return;
    const int head = lane >> 4;
    const float adh = ald[node * 4 + head];
    float ax = 0.f, ay = 0.f, az = 0.f, aw = 0.f, wsum = 0.f;
    const int beg = rowptr[node], end = rowptr[node + 1];
    int i = beg;
    for (; i + 2 <= end; i += 2) {
        int s0 = csr[i], s1 = csr[i + 1];
        float a0 = als[s0 * 4 + head], a1 = als[s1 * 4 + head];
        float4 v0 = *reinterpret_cast<const float4*>(h1 + (size_t)s0 * 256 + lane * 4);
        float4 v1 = *reinterpret_cast<const float4*>(h1 + (size_t)s1 * 256 + lane * 4);
        float w0 = expf(lrelu02(a0 + adh));
        float w1 = expf(lrelu02(a1 + adh));
        ax += w0 * v0.x + w1 * v1.x;
        ay += w0 * v0.y + w1 * v1.y;
        az += w0 * v0.z + w1 * v1.z;
        aw += w0 * v0.w + w1 * v1.w;
        wsum += w0 + w1;
    }
    if (i < end) {
        int s0 = csr[i];
        float a0 = als[s0 * 4 + head];
        float4 v0 = *reinterpret_cast<const float4*>(h1 + (size_t)s0 * 256 + lane * 4);
        float w0 = expf(lrelu02(a0 + adh));
        ax += w0 * v0.x; ay += w0 * v0.y; az += w0 * v0.z; aw += w0 * v0.w;
        wsum += w0;
    }
    {   // self loop
        float a0 = als[node * 4 + head];
        float4 v0 = *reinterpret_cast<const float4*>(h1 + (size_t)node * 256 + lane * 4);
        float w0 = expf(lrelu02(a0 + adh));
        ax += w0 * v0.x; ay += w0 * v0.y; az += w0 * v0.z; aw += w0 * v0.w;
        wsum += w0;
    }
    const float inv = 1.f / (wsum + 1e-16f);
    float4 bv = *reinterpret_cast<const float4*>(b1 + lane * 4);
    float4 r;
    r.x = elu1(ax * inv + bv.x);
    r.y = elu1(ay * inv + bv.y);
    r.z = elu1(az * inv + bv.z);
    r.w = elu1(aw * inv + bv.w);
    *reinterpret_cast<float4*>(x2 + (size_t)node * 256 + lane * 4) = r;
}

// ---------------- attention logits, layer 2 (single head over 64 ch) ----------------
__global__ void k_al2(const float* __restrict__ h2, const float* __restrict__ a_src,
                      const float* __restrict__ a_dst, float* __restrict__ als,
                      float* __restrict__ ald, int n) {
    const int lane = threadIdx.x & 63;
    const int node = (blockIdx.x << 2) + (threadIdx.x >> 6);
    if (node >= n) return;
    float hv = h2[(size_t)node * 64 + lane];
    float ps = hv * a_src[lane];
    float pd = hv * a_dst[lane];
#pragma unroll
    for (int d = 1; d < 64; d <<= 1) { ps += __shfl_xor(ps, d); pd += __shfl_xor(pd, d); }
    if (lane == 0) { als[node] = ps; ald[node] = pd; }
}

// ---------------- edge aggregation, layer 2 ----------------
__global__ void k_edge2(const float* __restrict__ h2, const float* __restrict__ als,
                        const float* __restrict__ ald, const int* __restrict__ rowptr,
                        const int* __restrict__ csr, const float* __restrict__ b2,
                        float* __restrict__ out2, int n) {
    const int lane = threadIdx.x & 63;
    const int node = (blockIdx.x << 2) + (threadIdx.x >> 6);
    if (node >= n) return;
    const float adh = ald[node];
    float acc = 0.f, wsum = 0.f;
    const int beg = rowptr[node], end = rowptr[node + 1];
    int i = beg;
    for (; i + 2 <= end; i += 2) {
        int s0 = csr[i], s1 = csr[i + 1];
        float a0 = als[s0], a1 = als[s1];
        float v0 = h2[(size_t)s0 * 64 + lane];
        float v1 = h2[(size_t)s1 * 64 + lane];
        float w0 = expf(lrelu02(a0 + adh));
        float w1 = expf(lrelu02(a1 + adh));
        acc += w0 * v0 + w1 * v1;
        wsum += w0 + w1;
    }
    if (i < end) {
        int s0 = csr[i];
        float w0 = expf(lrelu02(als[s0] + adh));
        acc += w0 * h2[(size_t)s0 * 64 + lane];
        wsum += w0;
    }
    {   // self loop
        float w0 = expf(lrelu02(als[node] + adh));
        acc += w0 * h2[(size_t)node * 64 + lane];
        wsum += w0;
    }
    float o = acc / (wsum + 1e-16f) + b2[lane];
    out2[(size_t)node * 64 + lane] = elu1(o);
}

// ---------------- pool (mean by sorted batch) + fc ----------------
__global__ __launch_bounds__(1024) void k_pool(const float* __restrict__ out2,
                                               const int* __restrict__ batch,
                                               const float* __restrict__ fcW,
                                               const float* __restrict__ fcb,
                                               float* __restrict__ out, int n) {
    __shared__ float sbuf[16][64];
    const int g = blockIdx.x;
    const int lane = threadIdx.x & 63, wv = threadIdx.x >> 6;
    int lo0 = 0, hi0 = n;
    while (lo0 < hi0) { int mid = (lo0 + hi0) >> 1; if (batch[mid] < g) lo0 = mid + 1; else hi0 = mid; }
    int lo1 = lo0, hi1 = n;
    while (lo1 < hi1) { int mid = (lo1 + hi1) >> 1; if (batch[mid] < g + 1) lo1 = mid + 1; else hi1 = mid; }
    float s0 = 0.f, s1 = 0.f;
    int r = lo0 + wv;
    for (; r + 16 < lo1; r += 32) {
        s0 += out2[(size_t)r * 64 + lane];
        s1 += out2[(size_t)(r + 16) * 64 + lane];
    }
    if (r < lo1) s0 += out2[(size_t)r * 64 + lane];
    sbuf[wv][lane] = s0 + s1;
    __syncthreads();
    if (wv == 0) {
        float s = 0.f;
#pragma unroll
        for (int k = 0; k < 16; ++k) s += sbuf[k][lane];
        float cntf = (float)(lo1 - lo0);
        float pooled = s / fmaxf(cntf, 1.f);
        float v = pooled * fcW[lane];
#pragma unroll
        for (int d = 32; d; d >>= 1) v += __shfl_xor(v, d);
        if (lane == 0) out[g] = v + fcb[0];
    }
}

// ---------------- host launcher ----------------
extern "C" void kernel_launch(void* const* d_in, const int* in_sizes, int n_in,
                              void* d_out, int out_size, void* d_ws, size_t ws_size,
                              hipStream_t stream) {
    const float* x      = (const float*)d_in[0];
    const int*   ei     = (const int*)  d_in[1];
    const int*   batch  = (const int*)  d_in[2];
    const float* W1     = (const float*)d_in[3];
    const float* a_src1 = (const float*)d_in[4];
    const float* a_dst1 = (const float*)d_in[5];
    const float* b1     = (const float*)d_in[6];
    const float* W2     = (const float*)d_in[7];
    const float* a_src2 = (const float*)d_in[8];
    const float* a_dst2 = (const float*)d_in[9];
    const float* b2     = (const float*)d_in[10];
    const float* fcW    = (const float*)d_in[11];
    const float* fcb    = (const float*)d_in[12];
    float* out = (float*)d_out;

    const int N = in_sizes[2];
    const int E = in_sizes[1] / 2;
    (void)n_in; (void)ws_size;

    char* ws = (char*)d_ws;
    size_t off = 0;
    auto alloc = [&](size_t bytes) -> char* {
        char* p = ws + off;
        off += (bytes + 255) & ~(size_t)255;
        return p;
    };
    int*   cnt    = (int*)  alloc((size_t)N * 4);
    int*   fill   = (int*)  alloc((size_t)N * 4);
    int*   rowptr = (int*)  alloc((size_t)(N + 1) * 4);
    int*   csr    = (int*)  alloc((size_t)E * 4);
    float* h1     = (float*)alloc((size_t)N * 256 * 4);
    float* x2     = (float*)alloc((size_t)N * 256 * 4);
    float* h2     = (float*)alloc((size_t)N * 64 * 4);
    float* out2   = (float*)alloc((size_t)N * 64 * 4);
    float* als1   = (float*)alloc((size_t)N * 4 * 4);
    float* ald1   = (float*)alloc((size_t)N * 4 * 4);
    float* als2   = (float*)alloc((size_t)N * 4);
    float* ald2   = (float*)alloc((size_t)N * 4);

    hipMemsetAsync(cnt, 0, (size_t)N * 4, stream);
    const int ge = (E + 255) / 256;
    k_hist<<<ge, 256, 0, stream>>>(ei + E, cnt, E);
    k_scan<<<1, 1024, 0, stream>>>(cnt, rowptr, fill, N);
    k_scatter<<<ge, 256, 0, stream>>>(ei, ei + E, fill, csr, E);

    // Layer 1: GEMM 50000x128 @ 128x256
    const int gm1 = (N + 127) / 128;
    k_gemm_t<128, 128, 16, 16, 16><<<gm1 * 2, 256, 0, stream>>>(x, W1, h1, N, 128, 256);
    const int gn4 = (N + 3) / 4;
    k_al1<<<gn4, 256, 0, stream>>>(h1, a_src1, a_dst1, als1, ald1, N);
    k_edge1<<<gn4, 256, 0, stream>>>(h1, als1, ald1, rowptr, csr, b1, x2, N);

    // Layer 2: GEMM 50000x256 @ 256x64
    k_gemm_t<128, 64, 16, 8, 16><<<gm1, 128, 0, stream>>>(x2, W2, h2, N, 256, 64);
    k_al2<<<gn4, 256, 0, stream>>>(h2, a_src2, a_dst2, als2, ald2, N);
    k_edge2<<<gn4, 256, 0, stream>>>(h2, als2, ald2, rowptr, csr, b2, out2, N);

    // Pool + FC
    k_pool<<<out_size, 1024, 0, stream>>>(out2, batch, fcW, fcb, out, N);
}

// Round 4
// 446.024 us; speedup vs baseline: 1.6286x; 1.1370x over previous
//
#include <hip/hip_runtime.h>
#include <hip/hip_fp16.h>
#include <cstddef>
#include <cstdint>

// N=50000, F_IN=128, HID=64, HEADS=4, E=800000, NG=64
// Layer1: x[N,128]@W1[128,256] -> h1(fp16); GAT agg -> x2 = elu(agg+b1) [N,256] fp32
// Layer2: x2@W2[256,64] -> h2(fp16); GAT agg -> out2 = elu(agg+b2) [N,64] fp32
// Pool: segment-mean by sorted batch -> [64,64]; fc -> [64]

#define LOG2E 1.4426950408889634f
__device__ __forceinline__ float lrelu02(float x) { return x >= 0.f ? x : 0.2f * x; }
__device__ __forceinline__ float elu1(float x)    { return x > 0.f ? x : expm1f(x); }
__device__ __forceinline__ float fexp(float x)    { return exp2f(x * LOG2E); }

// ---------------- CSR build (by destination) ----------------
__global__ void k_hist(const int* __restrict__ dst, int* __restrict__ cnt, int e) {
    int i = blockIdx.x * 256 + threadIdx.x;
    if (i < e) atomicAdd(&cnt[dst[i]], 1);
}

__global__ __launch_bounds__(1024) void k_scan(const int* __restrict__ cnt,
                                               int* __restrict__ rowptr,
                                               int* __restrict__ fill, int n) {
    __shared__ int wsums[16];
    const int t = threadIdx.x, lane = t & 63, wv = t >> 6;
    int carry = 0;
    if (t == 0) rowptr[0] = 0;
    for (int base = 0; base < n; base += 1024) {
        int i = base + t;
        int v = (i < n) ? cnt[i] : 0;
        int s = v;
#pragma unroll
        for (int d = 1; d < 64; d <<= 1) { int o = __shfl_up(s, d); if (lane >= d) s += o; }
        if (lane == 63) wsums[wv] = s;
        __syncthreads();
        if (t < 16) {
            int xx = wsums[t];
#pragma unroll
            for (int d = 1; d < 16; d <<= 1) { int o = __shfl_up(xx, d); if (t >= d) xx += o; }
            wsums[t] = xx;
        }
        __syncthreads();
        int add = carry + (wv > 0 ? wsums[wv - 1] : 0);
        int incl = s + add;
        if (i < n) { rowptr[i + 1] = incl; fill[i] = incl - v; }
        carry += wsums[15];
        __syncthreads();
    }
}

__global__ void k_scatter(const int* __restrict__ src, const int* __restrict__ dstArr,
                          int* __restrict__ fill, int* __restrict__ csr, int e) {
    int i = blockIdx.x * 256 + threadIdx.x;
    if (i < e) {
        int d = dstArr[i];
        int p = atomicAdd(&fill[d], 1);
        csr[p] = src[i];
    }
}

// ---------------- fp32 register-blocked GEMM, fp16 output ----------------
// A,B tiles in LDS (A k-major), 8x8 acc/thread, register prefetch.
// Requires: K % BK == 0, NC % BN == 0, BM == 8*TY, BN == 8*TX.
template <int BM, int BN, int BK, int TX, int TY>
__global__ __launch_bounds__(TX * TY) void k_gemm_h(const float* __restrict__ A,
                                                    const float* __restrict__ B,
                                                    __half* __restrict__ C,
                                                    int M, int K, int NC) {
    constexpr int NT = TX * TY;
    constexpr int LA = (BM * BK) / (4 * NT);
    constexpr int LB = (BK * BN) / (4 * NT);
    __shared__ float As[BK][BM + 4];
    __shared__ float Bs[BK][BN + 4];

    const int tid = threadIdx.x;
    const int tx = tid % TX, ty = tid / TX;
    const int nbn = NC / BN;
    const int bx = blockIdx.x / nbn;
    const int by = blockIdx.x % nbn;
    const int row0 = bx * BM, col0 = by * BN;

    float4 pa[LA], pb[LB];
    auto loadA = [&](int kc) {
#pragma unroll
        for (int i = 0; i < LA; ++i) {
            int g = tid + i * NT;
            int m = g / (BK / 4), kq = (g % (BK / 4)) * 4;
            int gr = row0 + m;
            pa[i] = (gr < M) ? *reinterpret_cast<const float4*>(A + (size_t)gr * K + kc + kq)
                             : make_float4(0.f, 0.f, 0.f, 0.f);
        }
    };
    auto loadB = [&](int kc) {
#pragma unroll
        for (int i = 0; i < LB; ++i) {
            int g = tid + i * NT;
            int k = g / (BN / 4), n4 = (g % (BN / 4)) * 4;
            pb[i] = *reinterpret_cast<const float4*>(B + (size_t)(kc + k) * NC + col0 + n4);
        }
    };
    auto storeLDS = [&]() {
#pragma unroll
        for (int i = 0; i < LA; ++i) {
            int g = tid + i * NT;
            int m = g / (BK / 4), kq = (g % (BK / 4)) * 4;
            As[kq + 0][m] = pa[i].x; As[kq + 1][m] = pa[i].y;
            As[kq + 2][m] = pa[i].z; As[kq + 3][m] = pa[i].w;
        }
#pragma unroll
        for (int i = 0; i < LB; ++i) {
            int g = tid + i * NT;
            int k = g / (BN / 4), n4 = (g % (BN / 4)) * 4;
            *reinterpret_cast<float4*>(&Bs[k][n4]) = pb[i];
        }
    };

    float acc[8][8];
#pragma unroll
    for (int i = 0; i < 8; ++i)
#pragma unroll
        for (int j = 0; j < 8; ++j) acc[i][j] = 0.f;

    loadA(0); loadB(0);
    storeLDS();
    __syncthreads();
    const int TI = K / BK;
    for (int t = 0; t < TI; ++t) {
        if (t + 1 < TI) { loadA((t + 1) * BK); loadB((t + 1) * BK); }
#pragma unroll
        for (int k = 0; k < BK; ++k) {
            float4 a0 = *reinterpret_cast<const float4*>(&As[k][ty * 8]);
            float4 a1 = *reinterpret_cast<const float4*>(&As[k][ty * 8 + 4]);
            float4 b0 = *reinterpret_cast<const float4*>(&Bs[k][tx * 8]);
            float4 b1 = *reinterpret_cast<const float4*>(&Bs[k][tx * 8 + 4]);
            float av[8] = {a0.x, a0.y, a0.z, a0.w, a1.x, a1.y, a1.z, a1.w};
            float bv[8] = {b0.x, b0.y, b0.z, b0.w, b1.x, b1.y, b1.z, b1.w};
#pragma unroll
            for (int i = 0; i < 8; ++i)
#pragma unroll
                for (int j = 0; j < 8; ++j) acc[i][j] = fmaf(av[i], bv[j], acc[i][j]);
        }
        if (t + 1 < TI) {
            __syncthreads();
            storeLDS();
            __syncthreads();
        }
    }
#pragma unroll
    for (int i = 0; i < 8; ++i) {
        int gr = row0 + ty * 8 + i;
        if (gr < M) {
            __half2 h0 = __floats2half2_rn(acc[i][0], acc[i][1]);
            __half2 h1 = __floats2half2_rn(acc[i][2], acc[i][3]);
            __half2 h2 = __floats2half2_rn(acc[i][4], acc[i][5]);
            __half2 h3 = __floats2half2_rn(acc[i][6], acc[i][7]);
            int4 p;
            p.x = *reinterpret_cast<int*>(&h0); p.y = *reinterpret_cast<int*>(&h1);
            p.z = *reinterpret_cast<int*>(&h2); p.w = *reinterpret_cast<int*>(&h3);
            *reinterpret_cast<int4*>(C + (size_t)gr * NC + col0 + tx * 8) = p;
        }
    }
}

__device__ __forceinline__ void load_h4(const __half* __restrict__ p, float2& lo, float2& hi) {
    float2 raw = *reinterpret_cast<const float2*>(p);   // 8B = 4 halves
    __half2* q = reinterpret_cast<__half2*>(&raw);
    lo = __half22float2(q[0]);
    hi = __half22float2(q[1]);
}

// ---------------- attention logits, layer 1 ----------------
__global__ void k_al1(const __half* __restrict__ h1, const float* __restrict__ a_src,
                      const float* __restrict__ a_dst, float* __restrict__ als,
                      float* __restrict__ ald, int n) {
    const int lane = threadIdx.x & 63;
    const int node = (blockIdx.x << 2) + (threadIdx.x >> 6);
    if (node >= n) return;
    const int head = lane >> 4;
    float2 lo, hi;
    load_h4(h1 + (size_t)node * 256 + lane * 4, lo, hi);
    float4 av = *reinterpret_cast<const float4*>(a_src + lane * 4);
    float4 dv = *reinterpret_cast<const float4*>(a_dst + lane * 4);
    float ps = lo.x * av.x + lo.y * av.y + hi.x * av.z + hi.y * av.w;
    float pd = lo.x * dv.x + lo.y * dv.y + hi.x * dv.z + hi.y * dv.w;
#pragma unroll
    for (int d = 1; d < 16; d <<= 1) { ps += __shfl_xor(ps, d); pd += __shfl_xor(pd, d); }
    if ((lane & 15) == 0) { als[node * 4 + head] = ps; ald[node * 4 + head] = pd; }
}

// ---------------- edge aggregation, layer 1 (wave per dst node, fp16 gather) ----------------
__global__ void k_edge1(const __half* __restrict__ h1, const float* __restrict__ als,
                        const float* __restrict__ ald, const int* __restrict__ rowptr,
                        const int* __restrict__ csr, const float* __restrict__ b1,
                        float* __restrict__ x2, int n) {
    const int lane = threadIdx.x & 63;
    const int node = (blockIdx.x << 2) + (threadIdx.x >> 6);
    if (node >= n) return;
    const int head = lane >> 4;
    const int ch = lane * 4;
    const float adh = ald[node * 4 + head];
    float ax = 0.f, ay = 0.f, az = 0.f, aw = 0.f, wsum = 0.f;
    const int beg = rowptr[node], end = rowptr[node + 1];
    int i = beg;
    for (; i + 2 <= end; i += 2) {
        int s0 = csr[i], s1 = csr[i + 1];
        float a0 = als[s0 * 4 + head], a1 = als[s1 * 4 + head];
        float2 l0, u0, l1, u1;
        load_h4(h1 + (size_t)s0 * 256 + ch, l0, u0);
        load_h4(h1 + (size_t)s1 * 256 + ch, l1, u1);
        float w0 = fexp(lrelu02(a0 + adh));
        float w1 = fexp(lrelu02(a1 + adh));
        ax += w0 * l0.x + w1 * l1.x;
        ay += w0 * l0.y + w1 * l1.y;
        az += w0 * u0.x + w1 * u1.x;
        aw += w0 * u0.y + w1 * u1.y;
        wsum += w0 + w1;
    }
    if (i < end) {
        int s0 = csr[i];
        float a0 = als[s0 * 4 + head];
        float2 l0, u0;
        load_h4(h1 + (size_t)s0 * 256 + ch, l0, u0);
        float w0 = fexp(lrelu02(a0 + adh));
        ax += w0 * l0.x; ay += w0 * l0.y; az += w0 * u0.x; aw += w0 * u0.y;
        wsum += w0;
    }
    {   // self loop
        float a0 = als[node * 4 + head];
        float2 l0, u0;
        load_h4(h1 + (size_t)node * 256 + ch, l0, u0);
        float w0 = fexp(lrelu02(a0 + adh));
        ax += w0 * l0.x; ay += w0 * l0.y; az += w0 * u0.x; aw += w0 * u0.y;
        wsum += w0;
    }
    const float inv = 1.f / (wsum + 1e-16f);
    float4 bv = *reinterpret_cast<const float4*>(b1 + ch);
    float4 r;
    r.x = elu1(ax * inv + bv.x);
    r.y = elu1(ay * inv + bv.y);
    r.z = elu1(az * inv + bv.z);
    r.w = elu1(aw * inv + bv.w);
    *reinterpret_cast<float4*>(x2 + (size_t)node * 256 + ch) = r;
}

// ---------------- attention logits, layer 2 ----------------
__global__ void k_al2(const __half* __restrict__ h2, const float* __restrict__ a_src,
                      const float* __restrict__ a_dst, float* __restrict__ als,
                      float* __restrict__ ald, int n) {
    const int lane = threadIdx.x & 63;
    const int node = (blockIdx.x << 2) + (threadIdx.x >> 6);
    if (node >= n) return;
    float hv = __half2float(h2[(size_t)node * 64 + lane]);
    float ps = hv * a_src[lane];
    float pd = hv * a_dst[lane];
#pragma unroll
    for (int d = 1; d < 64; d <<= 1) { ps += __shfl_xor(ps, d); pd += __shfl_xor(pd, d); }
    if (lane == 0) { als[node] = ps; ald[node] = pd; }
}

// ---------------- edge aggregation, layer 2 (fp16 gather) ----------------
__global__ void k_edge2(const __half* __restrict__ h2, const float* __restrict__ als,
                        const float* __restrict__ ald, const int* __restrict__ rowptr,
                        const int* __restrict__ csr, const float* __restrict__ b2,
                        float* __restrict__ out2, int n) {
    const int lane = threadIdx.x & 63;
    const int node = (blockIdx.x << 2) + (threadIdx.x >> 6);
    if (node >= n) return;
    const float adh = ald[node];
    float acc = 0.f, wsum = 0.f;
    const int beg = rowptr[node], end = rowptr[node + 1];
    int i = beg;
    for (; i + 2 <= end; i += 2) {
        int s0 = csr[i], s1 = csr[i + 1];
        float a0 = als[s0], a1 = als[s1];
        float v0 = __half2float(h2[(size_t)s0 * 64 + lane]);
        float v1 = __half2float(h2[(size_t)s1 * 64 + lane]);
        float w0 = fexp(lrelu02(a0 + adh));
        float w1 = fexp(lrelu02(a1 + adh));
        acc += w0 * v0 + w1 * v1;
        wsum += w0 + w1;
    }
    if (i < end) {
        int s0 = csr[i];
        float w0 = fexp(lrelu02(als[s0] + adh));
        acc += w0 * __half2float(h2[(size_t)s0 * 64 + lane]);
        wsum += w0;
    }
    {   // self loop
        float w0 = fexp(lrelu02(als[node] + adh));
        acc += w0 * __half2float(h2[(size_t)node * 64 + lane]);
        wsum += w0;
    }
    float o = acc / (wsum + 1e-16f) + b2[lane];
    out2[(size_t)node * 64 + lane] = elu1(o);
}

// ---------------- pool (mean by sorted batch) + fc ----------------
__global__ __launch_bounds__(1024) void k_pool(const float* __restrict__ out2,
                                               const int* __restrict__ batch,
                                               const float* __restrict__ fcW,
                                               const float* __restrict__ fcb,
                                               float* __restrict__ out, int n) {
    __shared__ float sbuf[16][64];
    const int g = blockIdx.x;
    const int lane = threadIdx.x & 63, wv = threadIdx.x >> 6;
    int lo0 = 0, hi0 = n;
    while (lo0 < hi0) { int mid = (lo0 + hi0) >> 1; if (batch[mid] < g) lo0 = mid + 1; else hi0 = mid; }
    int lo1 = lo0, hi1 = n;
    while (lo1 < hi1) { int mid = (lo1 + hi1) >> 1; if (batch[mid] < g + 1) lo1 = mid + 1; else hi1 = mid; }
    float s0 = 0.f, s1 = 0.f;
    int r = lo0 + wv;
    for (; r + 16 < lo1; r += 32) {
        s0 += out2[(size_t)r * 64 + lane];
        s1 += out2[(size_t)(r + 16) * 64 + lane];
    }
    if (r < lo1) s0 += out2[(size_t)r * 64 + lane];
    sbuf[wv][lane] = s0 + s1;
    __syncthreads();
    if (wv == 0) {
        float s = 0.f;
#pragma unroll
        for (int k = 0; k < 16; ++k) s += sbuf[k][lane];
        float cntf = (float)(lo1 - lo0);
        float pooled = s / fmaxf(cntf, 1.f);
        float v = pooled * fcW[lane];
#pragma unroll
        for (int d = 32; d; d >>= 1) v += __shfl_xor(v, d);
        if (lane == 0) out[g] = v + fcb[0];
    }
}

// ---------------- host launcher ----------------
extern "C" void kernel_launch(void* const* d_in, const int* in_sizes, int n_in,
                              void* d_out, int out_size, void* d_ws, size_t ws_size,
                              hipStream_t stream) {
    const float* x      = (const float*)d_in[0];
    const int*   ei     = (const int*)  d_in[1];
    const int*   batch  = (const int*)  d_in[2];
    const float* W1     = (const float*)d_in[3];
    const float* a_src1 = (const float*)d_in[4];
    const float* a_dst1 = (const float*)d_in[5];
    const float* b1     = (const float*)d_in[6];
    const float* W2     = (const float*)d_in[7];
    const float* a_src2 = (const float*)d_in[8];
    const float* a_dst2 = (const float*)d_in[9];
    const float* b2     = (const float*)d_in[10];
    const float* fcW    = (const float*)d_in[11];
    const float* fcb    = (const float*)d_in[12];
    float* out = (float*)d_out;

    const int N = in_sizes[2];
    const int E = in_sizes[1] / 2;
    (void)n_in; (void)ws_size;

    char* ws = (char*)d_ws;
    size_t off = 0;
    auto alloc = [&](size_t bytes) -> char* {
        char* p = ws + off;
        off += (bytes + 255) & ~(size_t)255;
        return p;
    };
    int*    cnt    = (int*)   alloc((size_t)N * 4);
    int*    fill   = (int*)   alloc((size_t)N * 4);
    int*    rowptr = (int*)   alloc((size_t)(N + 1) * 4);
    int*    csr    = (int*)   alloc((size_t)E * 4);
    __half* h1h    = (__half*)alloc((size_t)N * 256 * 2);
    float*  x2     = (float*) alloc((size_t)N * 256 * 4);
    __half* h2h    = (__half*)alloc((size_t)N * 64 * 2);
    float*  out2   = (float*) alloc((size_t)N * 64 * 4);
    float*  als1   = (float*) alloc((size_t)N * 4 * 4);
    float*  ald1   = (float*) alloc((size_t)N * 4 * 4);
    float*  als2   = (float*) alloc((size_t)N * 4);
    float*  ald2   = (float*) alloc((size_t)N * 4);

    hipMemsetAsync(cnt, 0, (size_t)N * 4, stream);
    const int ge = (E + 255) / 256;
    k_hist<<<ge, 256, 0, stream>>>(ei + E, cnt, E);
    k_scan<<<1, 1024, 0, stream>>>(cnt, rowptr, fill, N);
    k_scatter<<<ge, 256, 0, stream>>>(ei, ei + E, fill, csr, E);

    // Layer 1: GEMM 50000x128 @ 128x256 -> fp16 h1
    const int gm1 = (N + 127) / 128;
    k_gemm_h<128, 128, 16, 16, 16><<<gm1 * 2, 256, 0, stream>>>(x, W1, h1h, N, 128, 256);
    const int gn4 = (N + 3) / 4;
    k_al1<<<gn4, 256, 0, stream>>>(h1h, a_src1, a_dst1, als1, ald1, N);
    k_edge1<<<gn4, 256, 0, stream>>>(h1h, als1, ald1, rowptr, csr, b1, x2, N);

    // Layer 2: GEMM 50000x256 @ 256x64 -> fp16 h2
    k_gemm_h<128, 64, 16, 8, 16><<<gm1, 128, 0, stream>>>(x2, W2, h2h, N, 256, 64);
    k_al2<<<gn4, 256, 0, stream>>>(h2h, a_src2, a_dst2, als2, ald2, N);
    k_edge2<<<gn4, 256, 0, stream>>>(h2h, als2, ald2, rowptr, csr, b2, out2, N);

    // Pool + FC
    k_pool<<<out_size, 1024, 0, stream>>>(out2, batch, fcW, fcb, out, N);
}

// Round 5
// 341.379 us; speedup vs baseline: 2.1278x; 1.3065x over previous
//
#include <hip/hip_runtime.h>
#include <hip/hip_fp16.h>
#include <cstddef>
#include <cstdint>

// N=50000, F_IN=128, HID=64, HEADS=4, E=800000, NG=64
// Layer1: x16[N,128]@W1p -> h1(fp16) via MFMA; GAT agg -> x2 = elu(agg+b1) fp16 [N,256]
// Layer2: x2@W2p -> h2(fp16) via MFMA; GAT agg -> out2 = elu(agg+b2) fp32 [N,64]
// Pool: segment-mean by sorted batch -> [64,64]; fc -> [64]

#define LOG2E 1.4426950408889634f
__device__ __forceinline__ float lrelu02(float x) { return x >= 0.f ? x : 0.2f * x; }
__device__ __forceinline__ float elu1(float x)    { return x > 0.f ? x : expm1f(x); }
__device__ __forceinline__ float fexp(float x)    { return exp2f(x * LOG2E); }

typedef _Float16 f16x8 __attribute__((ext_vector_type(8)));
typedef float    f32x4 __attribute__((ext_vector_type(4)));

// ---------------- CSR build (by destination) ----------------
__global__ void k_hist(const int* __restrict__ dst, int* __restrict__ cnt, int e) {
    int i = blockIdx.x * 256 + threadIdx.x;
    if (i < e) atomicAdd(&cnt[dst[i]], 1);
}

__global__ __launch_bounds__(1024) void k_scan(const int* __restrict__ cnt,
                                               int* __restrict__ rowptr,
                                               int* __restrict__ fill, int n) {
    __shared__ int wsums[16];
    const int t = threadIdx.x, lane = t & 63, wv = t >> 6;
    int carry = 0;
    if (t == 0) rowptr[0] = 0;
    for (int base = 0; base < n; base += 1024) {
        int i = base + t;
        int v = (i < n) ? cnt[i] : 0;
        int s = v;
#pragma unroll
        for (int d = 1; d < 64; d <<= 1) { int o = __shfl_up(s, d); if (lane >= d) s += o; }
        if (lane == 63) wsums[wv] = s;
        __syncthreads();
        if (t < 16) {
            int xx = wsums[t];
#pragma unroll
            for (int d = 1; d < 16; d <<= 1) { int o = __shfl_up(xx, d); if (t >= d) xx += o; }
            wsums[t] = xx;
        }
        __syncthreads();
        int add = carry + (wv > 0 ? wsums[wv - 1] : 0);
        int incl = s + add;
        if (i < n) { rowptr[i + 1] = incl; fill[i] = incl - v; }
        carry += wsums[15];
        __syncthreads();
    }
}

__global__ void k_scatter(const int* __restrict__ src, const int* __restrict__ dstArr,
                          int* __restrict__ fill, int* __restrict__ csr, int e) {
    int i = blockIdx.x * 256 + threadIdx.x;
    if (i < e) {
        int d = dstArr[i];
        int p = atomicAdd(&fill[d], 1);
        csr[p] = src[i];
    }
}

// ---------------- fp32 -> fp16 convert (x) ----------------
__global__ void k_cvt16(const float* __restrict__ in, __half* __restrict__ outp, int n4) {
    int i = blockIdx.x * 256 + threadIdx.x;
    if (i >= n4) return;
    float4 v = *reinterpret_cast<const float4*>(in + (size_t)i * 4);
    __half2 h0 = __floats2half2_rn(v.x, v.y);
    __half2 h1 = __floats2half2_rn(v.z, v.w);
    int2 p;
    p.x = *reinterpret_cast<int*>(&h0);
    p.y = *reinterpret_cast<int*>(&h1);
    *reinterpret_cast<int2*>(outp + (size_t)i * 4) = p;
}

// ---------------- W pack: fp32 [K][N] row-major -> fragment-ordered fp16 ----------------
// Packed index i = ((t*(N/16)+nt)*4 + q)*16 + c ; 8 contiguous halves = B[32t+8q+j][16nt+c]
__global__ void k_packW(const float* __restrict__ W, __half* __restrict__ Bp, int K, int N) {
    int i = blockIdx.x * 256 + threadIdx.x;
    int total = (K / 32) * (N / 16) * 64;
    if (i >= total) return;
    int c = i & 15, q = (i >> 4) & 3, tnt = i >> 6;
    int nt = tnt % (N / 16), t = tnt / (N / 16);
    int k0 = t * 32 + q * 8, col = nt * 16 + c;
    __half tmp[8];
#pragma unroll
    for (int j = 0; j < 8; ++j) tmp[j] = __float2half(W[(size_t)(k0 + j) * N + col]);
    *reinterpret_cast<int4*>(Bp + (size_t)i * 8) = *reinterpret_cast<int4*>(tmp);
}

// ---------------- MFMA GEMM: C[M,N] = A[M,K] @ B[K,N], all fp16 in, fp16 out ----------------
// Wave computes a 16-row x N-col stripe. A-frag: lane row=(l&15), k=8*(l>>4)+j.
// B from packed layout (see k_packW). D: col=lane&15, row=(lane>>4)*4+reg (HW-verified).
template <int K, int N>
__global__ __launch_bounds__(256) void k_gemm_mfma(const __half* __restrict__ A,
                                                   const __half* __restrict__ Bp,
                                                   __half* __restrict__ C, int M) {
    constexpr int NT = N / 16, KT = K / 32;
    const int lane = threadIdx.x & 63;
    const int wv = threadIdx.x >> 6;
    const int row0 = (blockIdx.x * 4 + wv) * 16;
    if (row0 >= M) return;

    f32x4 acc[NT];
#pragma unroll
    for (int nt = 0; nt < NT; ++nt) acc[nt] = (f32x4){0.f, 0.f, 0.f, 0.f};

    const __half* Ab = A + (size_t)(row0 + (lane & 15)) * K + (lane >> 4) * 8;
    const __half* Bb = Bp + (size_t)lane * 8;
#pragma unroll
    for (int t = 0; t < KT; ++t) {
        f16x8 a = *reinterpret_cast<const f16x8*>(Ab + t * 32);
#pragma unroll
        for (int nt = 0; nt < NT; ++nt) {
            f16x8 b = *reinterpret_cast<const f16x8*>(Bb + (size_t)(t * NT + nt) * 512);
            acc[nt] = __builtin_amdgcn_mfma_f32_16x16x32_f16(a, b, acc[nt], 0, 0, 0);
        }
    }
    const int r0 = row0 + (lane >> 4) * 4;
    const int cl = lane & 15;
#pragma unroll
    for (int nt = 0; nt < NT; ++nt) {
        int col = nt * 16 + cl;
#pragma unroll
        for (int j = 0; j < 4; ++j)
            C[(size_t)(r0 + j) * N + col] = __float2half(acc[nt][j]);
    }
}

__device__ __forceinline__ void load_h4(const __half* __restrict__ p, float2& lo, float2& hi) {
    float2 raw = *reinterpret_cast<const float2*>(p);   // 8B = 4 halves
    __half2* q = reinterpret_cast<__half2*>(&raw);
    lo = __half22float2(q[0]);
    hi = __half22float2(q[1]);
}

// ---------------- attention logits, layer 1 ----------------
__global__ void k_al1(const __half* __restrict__ h1, const float* __restrict__ a_src,
                      const float* __restrict__ a_dst, float* __restrict__ als,
                      float* __restrict__ ald, int n) {
    const int lane = threadIdx.x & 63;
    const int node = (blockIdx.x << 2) + (threadIdx.x >> 6);
    if (node >= n) return;
    const int head = lane >> 4;
    float2 lo, hi;
    load_h4(h1 + (size_t)node * 256 + lane * 4, lo, hi);
    float4 av = *reinterpret_cast<const float4*>(a_src + lane * 4);
    float4 dv = *reinterpret_cast<const float4*>(a_dst + lane * 4);
    float ps = lo.x * av.x + lo.y * av.y + hi.x * av.z + hi.y * av.w;
    float pd = lo.x * dv.x + lo.y * dv.y + hi.x * dv.z + hi.y * dv.w;
#pragma unroll
    for (int d = 1; d < 16; d <<= 1) { ps += __shfl_xor(ps, d); pd += __shfl_xor(pd, d); }
    if ((lane & 15) == 0) { als[node * 4 + head] = ps; ald[node * 4 + head] = pd; }
}

// ---------------- edge aggregation, layer 1 (fp16 gather, fp16 x2 out) ----------------
__global__ void k_edge1(const __half* __restrict__ h1, const float* __restrict__ als,
                        const float* __restrict__ ald, const int* __restrict__ rowptr,
                        const int* __restrict__ csr, const float* __restrict__ b1,
                        __half* __restrict__ x2, int n) {
    const int lane = threadIdx.x & 63;
    const int node = (blockIdx.x << 2) + (threadIdx.x >> 6);
    if (node >= n) return;
    const int head = lane >> 4;
    const int ch = lane * 4;
    const float adh = ald[node * 4 + head];
    float ax = 0.f, ay = 0.f, az = 0.f, aw = 0.f, wsum = 0.f;
    const int beg = rowptr[node], end = rowptr[node + 1];
    int i = beg;
    for (; i + 2 <= end; i += 2) {
        int s0 = csr[i], s1 = csr[i + 1];
        float a0 = als[s0 * 4 + head], a1 = als[s1 * 4 + head];
        float2 l0, u0, l1, u1;
        load_h4(h1 + (size_t)s0 * 256 + ch, l0, u0);
        load_h4(h1 + (size_t)s1 * 256 + ch, l1, u1);
        float w0 = fexp(lrelu02(a0 + adh));
        float w1 = fexp(lrelu02(a1 + adh));
        ax += w0 * l0.x + w1 * l1.x;
        ay += w0 * l0.y + w1 * l1.y;
        az += w0 * u0.x + w1 * u1.x;
        aw += w0 * u0.y + w1 * u1.y;
        wsum += w0 + w1;
    }
    if (i < end) {
        int s0 = csr[i];
        float a0 = als[s0 * 4 + head];
        float2 l0, u0;
        load_h4(h1 + (size_t)s0 * 256 + ch, l0, u0);
        float w0 = fexp(lrelu02(a0 + adh));
        ax += w0 * l0.x; ay += w0 * l0.y; az += w0 * u0.x; aw += w0 * u0.y;
        wsum += w0;
    }
    {   // self loop
        float a0 = als[node * 4 + head];
        float2 l0, u0;
        load_h4(h1 + (size_t)node * 256 + ch, l0, u0);
        float w0 = fexp(lrelu02(a0 + adh));
        ax += w0 * l0.x; ay += w0 * l0.y; az += w0 * u0.x; aw += w0 * u0.y;
        wsum += w0;
    }
    const float inv = 1.f / (wsum + 1e-16f);
    float4 bv = *reinterpret_cast<const float4*>(b1 + ch);
    __half2 r0 = __floats2half2_rn(elu1(ax * inv + bv.x), elu1(ay * inv + bv.y));
    __half2 r1 = __floats2half2_rn(elu1(az * inv + bv.z), elu1(aw * inv + bv.w));
    int2 p;
    p.x = *reinterpret_cast<int*>(&r0);
    p.y = *reinterpret_cast<int*>(&r1);
    *reinterpret_cast<int2*>(x2 + (size_t)node * 256 + ch) = p;
}

// ---------------- attention logits, layer 2 ----------------
__global__ void k_al2(const __half* __restrict__ h2, const float* __restrict__ a_src,
                      const float* __restrict__ a_dst, float* __restrict__ als,
                      float* __restrict__ ald, int n) {
    const int lane = threadIdx.x & 63;
    const int node = (blockIdx.x << 2) + (threadIdx.x >> 6);
    if (node >= n) return;
    float hv = __half2float(h2[(size_t)node * 64 + lane]);
    float ps = hv * a_src[lane];
    float pd = hv * a_dst[lane];
#pragma unroll
    for (int d = 1; d < 64; d <<= 1) { ps += __shfl_xor(ps, d); pd += __shfl_xor(pd, d); }
    if (lane == 0) { als[node] = ps; ald[node] = pd; }
}

// ---------------- edge aggregation, layer 2 (fp16 gather) ----------------
__global__ void k_edge2(const __half* __restrict__ h2, const float* __restrict__ als,
                        const float* __restrict__ ald, const int* __restrict__ rowptr,
                        const int* __restrict__ csr, const float* __restrict__ b2,
                        float* __restrict__ out2, int n) {
    const int lane = threadIdx.x & 63;
    const int node = (blockIdx.x << 2) + (threadIdx.x >> 6);
    if (node >= n) return;
    const float adh = ald[node];
    float acc = 0.f, wsum = 0.f;
    const int beg = rowptr[node], end = rowptr[node + 1];
    int i = beg;
    for (; i + 2 <= end; i += 2) {
        int s0 = csr[i], s1 = csr[i + 1];
        float a0 = als[s0], a1 = als[s1];
        float v0 = __half2float(h2[(size_t)s0 * 64 + lane]);
        float v1 = __half2float(h2[(size_t)s1 * 64 + lane]);
        float w0 = fexp(lrelu02(a0 + adh));
        float w1 = fexp(lrelu02(a1 + adh));
        acc += w0 * v0 + w1 * v1;
        wsum += w0 + w1;
    }
    if (i < end) {
        int s0 = csr[i];
        float w0 = fexp(lrelu02(als[s0] + adh));
        acc += w0 * __half2float(h2[(size_t)s0 * 64 + lane]);
        wsum += w0;
    }
    {   // self loop
        float w0 = fexp(lrelu02(als[node] + adh));
        acc += w0 * __half2float(h2[(size_t)node * 64 + lane]);
        wsum += w0;
    }
    float o = acc / (wsum + 1e-16f) + b2[lane];
    out2[(size_t)node * 64 + lane] = elu1(o);
}

// ---------------- pool (mean by sorted batch) + fc ----------------
__global__ __launch_bounds__(1024) void k_pool(const float* __restrict__ out2,
                                               const int* __restrict__ batch,
                                               const float* __restrict__ fcW,
                                               const float* __restrict__ fcb,
                                               float* __restrict__ out, int n) {
    __shared__ float sbuf[16][64];
    const int g = blockIdx.x;
    const int lane = threadIdx.x & 63, wv = threadIdx.x >> 6;
    int lo0 = 0, hi0 = n;
    while (lo0 < hi0) { int mid = (lo0 + hi0) >> 1; if (batch[mid] < g) lo0 = mid + 1; else hi0 = mid; }
    int lo1 = lo0, hi1 = n;
    while (lo1 < hi1) { int mid = (lo1 + hi1) >> 1; if (batch[mid] < g + 1) lo1 = mid + 1; else hi1 = mid; }
    float s0 = 0.f, s1 = 0.f;
    int r = lo0 + wv;
    for (; r + 16 < lo1; r += 32) {
        s0 += out2[(size_t)r * 64 + lane];
        s1 += out2[(size_t)(r + 16) * 64 + lane];
    }
    if (r < lo1) s0 += out2[(size_t)r * 64 + lane];
    sbuf[wv][lane] = s0 + s1;
    __syncthreads();
    if (wv == 0) {
        float s = 0.f;
#pragma unroll
        for (int k = 0; k < 16; ++k) s += sbuf[k][lane];
        float cntf = (float)(lo1 - lo0);
        float pooled = s / fmaxf(cntf, 1.f);
        float v = pooled * fcW[lane];
#pragma unroll
        for (int d = 32; d; d >>= 1) v += __shfl_xor(v, d);
        if (lane == 0) out[g] = v + fcb[0];
    }
}

// ---------------- host launcher ----------------
extern "C" void kernel_launch(void* const* d_in, const int* in_sizes, int n_in,
                              void* d_out, int out_size, void* d_ws, size_t ws_size,
                              hipStream_t stream) {
    const float* x      = (const float*)d_in[0];
    const int*   ei     = (const int*)  d_in[1];
    const int*   batch  = (const int*)  d_in[2];
    const float* W1     = (const float*)d_in[3];
    const float* a_src1 = (const float*)d_in[4];
    const float* a_dst1 = (const float*)d_in[5];
    const float* b1     = (const float*)d_in[6];
    const float* W2     = (const float*)d_in[7];
    const float* a_src2 = (const float*)d_in[8];
    const float* a_dst2 = (const float*)d_in[9];
    const float* b2     = (const float*)d_in[10];
    const float* fcW    = (const float*)d_in[11];
    const float* fcb    = (const float*)d_in[12];
    float* out = (float*)d_out;

    const int N = in_sizes[2];
    const int E = in_sizes[1] / 2;
    (void)n_in; (void)ws_size;

    char* ws = (char*)d_ws;
    size_t off = 0;
    auto alloc = [&](size_t bytes) -> char* {
        char* p = ws + off;
        off += (bytes + 255) & ~(size_t)255;
        return p;
    };
    int*    cnt    = (int*)   alloc((size_t)N * 4);
    int*    fill   = (int*)   alloc((size_t)N * 4);
    int*    rowptr = (int*)   alloc((size_t)(N + 1) * 4);
    int*    csr    = (int*)   alloc((size_t)E * 4);
    __half* xh     = (__half*)alloc((size_t)N * 128 * 2);
    __half* W1p    = (__half*)alloc((size_t)128 * 256 * 2);
    __half* W2p    = (__half*)alloc((size_t)256 * 64 * 2);
    __half* h1h    = (__half*)alloc((size_t)N * 256 * 2);
    __half* x2h    = (__half*)alloc((size_t)N * 256 * 2);
    __half* h2h    = (__half*)alloc((size_t)N * 64 * 2);
    float*  out2   = (float*) alloc((size_t)N * 64 * 4);
    float*  als1   = (float*) alloc((size_t)N * 4 * 4);
    float*  ald1   = (float*) alloc((size_t)N * 4 * 4);
    float*  als2   = (float*) alloc((size_t)N * 4);
    float*  ald2   = (float*) alloc((size_t)N * 4);

    hipMemsetAsync(cnt, 0, (size_t)N * 4, stream);
    const int ge = (E + 255) / 256;
    k_hist<<<ge, 256, 0, stream>>>(ei + E, cnt, E);
    k_scan<<<1, 1024, 0, stream>>>(cnt, rowptr, fill, N);
    k_scatter<<<ge, 256, 0, stream>>>(ei, ei + E, fill, csr, E);

    // fp16 conversions / weight packing
    const int n4x = N * 128 / 4;
    k_cvt16<<<(n4x + 255) / 256, 256, 0, stream>>>(x, xh, n4x);
    k_packW<<<(4096 + 255) / 256, 256, 0, stream>>>(W1, W1p, 128, 256);
    k_packW<<<(2048 + 255) / 256, 256, 0, stream>>>(W2, W2p, 256, 64);

    // Layer 1: MFMA GEMM [N,128]@[128,256] -> fp16 h1
    const int gw = (N / 16 + 3) / 4;   // 16 rows per wave, 4 waves per block
    k_gemm_mfma<128, 256><<<gw, 256, 0, stream>>>(xh, W1p, h1h, N);
    const int gn4 = (N + 3) / 4;
    k_al1<<<gn4, 256, 0, stream>>>(h1h, a_src1, a_dst1, als1, ald1, N);
    k_edge1<<<gn4, 256, 0, stream>>>(h1h, als1, ald1, rowptr, csr, b1, x2h, N);

    // Layer 2: MFMA GEMM [N,256]@[256,64] -> fp16 h2
    k_gemm_mfma<256, 64><<<gw, 256, 0, stream>>>(x2h, W2p, h2h, N);
    k_al2<<<gn4, 256, 0, stream>>>(h2h, a_src2, a_dst2, als2, ald2, N);
    k_edge2<<<gn4, 256, 0, stream>>>(h2h, als2, ald2, rowptr, csr, b2, out2, N);

    // Pool + FC
    k_pool<<<out_size, 1024, 0, stream>>>(out2, batch, fcW, fcb, out, N);
}